// Round 1
// baseline (100.685 us; speedup 1.0000x reference)
//
#include <hip/hip_runtime.h>
#include <hip/hip_bf16.h>
#include <stdint.h>

// ComplexDFT256: out(65536x512) = X(65536x512) @ W^T, W = [[cos,-sin],[sin,cos]] in bf16.

typedef __attribute__((ext_vector_type(8))) short bf16x8;
typedef __attribute__((ext_vector_type(4))) float f32x4;

#define KDIM 512
#define NDIM 512
#define BM 64

__device__ __forceinline__ ushort f2bf(float f) {
  union { float f; uint32_t u; } v; v.f = f;
  // round-to-nearest-even bf16
  uint32_t r = (v.u + 0x7fffu + ((v.u >> 16) & 1u)) >> 16;
  return (ushort)r;
}

// Build W (512x512 bf16, row-major [j][k]) from the fp32 cos/sin tables.
__global__ __launch_bounds__(256) void build_w_kernel(const float* __restrict__ cosk,
                                                      const float* __restrict__ sink,
                                                      ushort* __restrict__ W) {
  int idx = blockIdx.x * 256 + threadIdx.x;   // 0 .. 262143
  int j = idx >> 9;
  int k = idx & 511;
  float v;
  if (j < 256) {
    v = (k < 256) ? cosk[(j << 8) + k] : -sink[(j << 8) + (k - 256)];
  } else {
    int jj = j - 256;
    v = (k < 256) ? sink[(jj << 8) + k] : cosk[(jj << 8) + (k - 256)];
  }
  W[idx] = f2bf(v);
}

// GEMM: block = 64 rows x 512 cols (full N), 8 waves, each wave 64x64.
// K-loop: 8 steps of BK=64. A staged in LDS (bf16, XOR-swizzled); W read from L2.
__global__ __launch_bounds__(512, 2) void dft_gemm_kernel(const float* __restrict__ A,
                                                          const ushort* __restrict__ W,
                                                          float* __restrict__ out) {
  __shared__ ushort As[BM * 64];   // 8 KB, swizzled: elem idx ^= (row&7)<<3

  const int tid  = threadIdx.x;
  const int lane = tid & 63;
  const int wid  = tid >> 6;            // 0..7
  const int m0   = blockIdx.x * BM;
  const int c0   = wid * 64;

  // --- staging indices: 512 threads, each 8 floats (two float4) of one row ---
  const int srow = tid >> 3;            // 0..63
  const int skq  = (tid & 7) * 8;       // k-elem offset within 64-wide tile
  const float* ap = A + (m0 + srow) * KDIM + skq;
  int swidx = (srow << 6) + (skq ^ ((srow & 7) << 3));

  // --- fragment indices ---
  const int lrow = lane & 15;
  const int lk8  = (lane >> 4) * 8;     // k offset within 32

  const ushort* wb[4];
#pragma unroll
  for (int ni = 0; ni < 4; ++ni)
    wb[ni] = W + (c0 + ni * 16 + lrow) * KDIM + lk8;

  f32x4 acc[4][4] = {};

  // prefetch K-tile 0
  f32x4 p0 = *reinterpret_cast<const f32x4*>(ap);
  f32x4 p1 = *reinterpret_cast<const f32x4*>(ap + 4);

  for (int t = 0; t < 8; ++t) {
    // convert + LDS write (consumes p0/p1)
    bf16x8 w8;
    w8[0] = (short)f2bf(p0[0]);
    w8[1] = (short)f2bf(p0[1]);
    w8[2] = (short)f2bf(p0[2]);
    w8[3] = (short)f2bf(p0[3]);
    w8[4] = (short)f2bf(p1[0]);
    w8[5] = (short)f2bf(p1[1]);
    w8[6] = (short)f2bf(p1[2]);
    w8[7] = (short)f2bf(p1[3]);
    *reinterpret_cast<bf16x8*>(&As[swidx]) = w8;
    __syncthreads();

    // issue next tile's global loads; they complete under the MFMAs below
    if (t < 7) {
      const float* apn = ap + (t + 1) * 64;
      p0 = *reinterpret_cast<const f32x4*>(apn);
      p1 = *reinterpret_cast<const f32x4*>(apn + 4);
    }

#pragma unroll
    for (int kk = 0; kk < 2; ++kk) {
      bf16x8 afr[4], bfr[4];
#pragma unroll
      for (int mi = 0; mi < 4; ++mi) {
        int row = mi * 16 + lrow;
        int idx = (row << 6) + ((kk * 32 + lk8) ^ ((lrow & 7) << 3));
        afr[mi] = *reinterpret_cast<const bf16x8*>(&As[idx]);
      }
#pragma unroll
      for (int ni = 0; ni < 4; ++ni)
        bfr[ni] = *reinterpret_cast<const bf16x8*>(wb[ni] + t * 64 + kk * 32);
#pragma unroll
      for (int mi = 0; mi < 4; ++mi)
#pragma unroll
        for (int ni = 0; ni < 4; ++ni)
          acc[mi][ni] = __builtin_amdgcn_mfma_f32_16x16x32_bf16(afr[mi], bfr[ni],
                                                                acc[mi][ni], 0, 0, 0);
    }
    __syncthreads();
  }

  // epilogue: C/D layout col = lane&15, row = (lane>>4)*4 + r
  const int orow0 = m0 + (lane >> 4) * 4;
#pragma unroll
  for (int mi = 0; mi < 4; ++mi) {
#pragma unroll
    for (int ni = 0; ni < 4; ++ni) {
      int col = c0 + ni * 16 + lrow;
      float* op = out + (size_t)(orow0 + mi * 16) * NDIM + col;
#pragma unroll
      for (int r = 0; r < 4; ++r)
        op[(size_t)r * NDIM] = acc[mi][ni][r];
    }
  }
}

extern "C" void kernel_launch(void* const* d_in, const int* in_sizes, int n_in,
                              void* d_out, int out_size, void* d_ws, size_t ws_size,
                              hipStream_t stream) {
  const float* x    = (const float*)d_in[0];   // (65536, 2, 256) fp32 == (65536, 512)
  const float* cosk = (const float*)d_in[1];   // (256, 256) fp32
  const float* sink = (const float*)d_in[2];   // (256, 256) fp32
  float* out = (float*)d_out;                  // (65536, 512, 1) fp32
  ushort* W  = (ushort*)d_ws;                  // 512*512 bf16 = 512 KB scratch

  // 1) build bf16 weight matrix (deterministic every call)
  build_w_kernel<<<1024, 256, 0, stream>>>(cosk, sink, W);

  // 2) GEMM
  dft_gemm_kernel<<<65536 / BM, 512, 0, stream>>>(x, W, out);
}

// Round 5
// 72.736 us; speedup vs baseline: 1.3843x; 1.3843x over previous
//
#include <hip/hip_runtime.h>
#include <hip/hip_bf16.h>
#include <stdint.h>

// ComplexDFT256: out(65536x512) = X(65536x512) @ W^T, W = [[cos,-sin],[sin,cos]].
// Computed transposed via MFMA operand swap: D[j][b] with j contiguous per lane.

typedef __attribute__((ext_vector_type(8))) short bf16x8;
typedef __attribute__((ext_vector_type(4))) float f32x4;

#define KDIM 512
#define NDIM 512
#define BM 64

__device__ __forceinline__ ushort f2bf(float f) {
  union { float f; uint32_t u; } v; v.f = f;
  uint32_t r = (v.u + 0x7fffu + ((v.u >> 16) & 1u)) >> 16;  // RNE
  return (ushort)r;
}

// Fragment-ordered W: Wf[8*g .. 8*g+7], g = k5*2048 + nt*64 + lane, holds
// W[j = nt*16 + (lane&15)][k = k5*32 + (lane>>4)*8 + e]  (e = 0..7)
__global__ __launch_bounds__(512) void build_w_kernel(const float* __restrict__ cosk,
                                                      const float* __restrict__ sink,
                                                      ushort* __restrict__ Wf) {
  int g = blockIdx.x * 512 + threadIdx.x;   // 0..32767
  int lane = g & 63;
  int nt = (g >> 6) & 31;
  int j = nt * 16 + (lane & 15);
  int kbase = (g >> 11) * 32 + (lane >> 4) * 8;
  bf16x8 w8;
#pragma unroll
  for (int e = 0; e < 8; ++e) {
    int k = kbase + e;
    float v;
    if (j < 256) {
      v = (k < 256) ? cosk[(j << 8) + k] : -sink[(j << 8) + (k - 256)];
    } else {
      int jj = j - 256;
      v = (k < 256) ? sink[(jj << 8) + k] : cosk[(jj << 8) + (k - 256)];
    }
    w8[e] = (short)f2bf(v);
  }
  *reinterpret_cast<bf16x8*>(Wf + (size_t)g * 8) = w8;
}

__device__ __forceinline__ bf16x8 cvt8(f32x4 a, f32x4 b) {
  bf16x8 w8;
  w8[0] = (short)f2bf(a[0]); w8[1] = (short)f2bf(a[1]);
  w8[2] = (short)f2bf(a[2]); w8[3] = (short)f2bf(a[3]);
  w8[4] = (short)f2bf(b[0]); w8[5] = (short)f2bf(b[1]);
  w8[6] = (short)f2bf(b[2]); w8[7] = (short)f2bf(b[3]);
  return w8;
}

// Block = 64 batch rows x full 512 output cols, 8 waves (each 64 j x 64 b).
// X staged in double-buffered LDS (bf16, XOR-swizzled); W frags streamed from L2.
// Raw s_barrier + lgkmcnt(0) only -> global loads stay in flight across barriers.
__global__ __launch_bounds__(512) void dft_gemm_kernel(const float* __restrict__ A,
                                                       const ushort* __restrict__ Wf,
                                                       float* __restrict__ out) {
  __shared__ ushort As[2][BM * 64];   // 2 x 8 KB

  const int tid  = threadIdx.x;
  const int lane = tid & 63;
  const int wid  = tid >> 6;            // 0..7
  const int m0   = blockIdx.x * BM;     // batch-row base
  const int c0   = wid * 64;            // j base for this wave

  // staging: 512 threads, each 8 floats (two f32x4) of one row per K-tile
  const int srow = tid >> 3;
  const int skq  = (tid & 7) * 8;
  const float* ap = A + (size_t)(m0 + srow) * KDIM + skq;
  const int swidx = (srow << 6) + (skq ^ ((srow & 7) << 3));

  const int lrow = lane & 15;
  const int lk8  = (lane >> 4) * 8;

  // W frag base: (k5*32 + nt)*512 + lane*8 elems; nt = c0/16 + mi, k5 = t*2 + kk
  const ushort* wp = Wf + (size_t)(c0 >> 4) * 512 + lane * 8;

  f32x4 acc[4][4] = {};   // acc[mi][ni]: mi = j-tile, ni = b-tile

  // ---- prologue: tile 0 -> LDS[0], tile 1 in flight ----
  f32x4 q0 = *reinterpret_cast<const f32x4*>(ap);
  f32x4 q1 = *reinterpret_cast<const f32x4*>(ap + 4);
  f32x4 p0 = *reinterpret_cast<const f32x4*>(ap + 64);
  f32x4 p1 = *reinterpret_cast<const f32x4*>(ap + 68);
  *reinterpret_cast<bf16x8*>(&As[0][swidx]) = cvt8(q0, q1);
  asm volatile("s_waitcnt lgkmcnt(0)" ::: "memory");
  __builtin_amdgcn_s_barrier();

#pragma unroll
  for (int t = 0; t < 8; ++t) {
    // 1) write next X tile to the other buffer (waits on p via auto vmcnt)
    if (t < 7)
      *reinterpret_cast<bf16x8*>(&As[(t + 1) & 1][swidx]) = cvt8(p0, p1);

    // 2) issue all 8 W frag loads for this K-step (coalesced 1KB streams from L2)
    bf16x8 wfr[2][4];
#pragma unroll
    for (int kk = 0; kk < 2; ++kk)
#pragma unroll
      for (int mi = 0; mi < 4; ++mi)
        wfr[kk][mi] = *reinterpret_cast<const bf16x8*>(
            wp + (size_t)((t * 2 + kk) * 32 + mi) * 512);

    // 3) issue X tile t+2 (lands ~1 full iteration later; issued after W so
    //    the MFMAs' vmcnt waits for W never drain it)
    if (t < 6) {
      p0 = *reinterpret_cast<const f32x4*>(ap + (t + 2) * 64);
      p1 = *reinterpret_cast<const f32x4*>(ap + (t + 2) * 64 + 4);
    }

    // 4) LDS reads + MFMAs
#pragma unroll
    for (int kk = 0; kk < 2; ++kk) {
      bf16x8 xfr[4];
#pragma unroll
      for (int ni = 0; ni < 4; ++ni) {
        int row = ni * 16 + lrow;
        int idx = (row << 6) + ((kk * 32 + lk8) ^ ((lrow & 7) << 3));
        xfr[ni] = *reinterpret_cast<const bf16x8*>(&As[t & 1][idx]);
      }
#pragma unroll
      for (int mi = 0; mi < 4; ++mi)
#pragma unroll
        for (int ni = 0; ni < 4; ++ni)
          acc[mi][ni] = __builtin_amdgcn_mfma_f32_16x16x32_bf16(
              wfr[kk][mi], xfr[ni], acc[mi][ni], 0, 0, 0);
    }

    // 5) single barrier per K-step; only LDS drained (vmem stays in flight)
    if (t < 7) {
      asm volatile("s_waitcnt lgkmcnt(0)" ::: "memory");
      __builtin_amdgcn_s_barrier();
    }
  }

  // ---- epilogue: lane holds 4 contiguous j's -> f32x4 stores ----
  const int jbase = c0 + (lane >> 4) * 4;
#pragma unroll
  for (int ni = 0; ni < 4; ++ni) {
    size_t rowb = (size_t)(m0 + ni * 16 + lrow) * NDIM;
#pragma unroll
    for (int mi = 0; mi < 4; ++mi)
      *reinterpret_cast<f32x4*>(out + rowb + jbase + mi * 16) = acc[mi][ni];
  }
}

extern "C" void kernel_launch(void* const* d_in, const int* in_sizes, int n_in,
                              void* d_out, int out_size, void* d_ws, size_t ws_size,
                              hipStream_t stream) {
  const float* x    = (const float*)d_in[0];   // (65536, 2, 256) fp32
  const float* cosk = (const float*)d_in[1];   // (256, 256) fp32
  const float* sink = (const float*)d_in[2];   // (256, 256) fp32
  float* out = (float*)d_out;                  // (65536, 512, 1) fp32
  ushort* Wf = (ushort*)d_ws;                  // 512 KB fragment-ordered W

  build_w_kernel<<<64, 512, 0, stream>>>(cosk, sink, Wf);
  dft_gemm_kernel<<<65536 / BM, 512, 0, stream>>>(x, Wf, out);
}

// Round 6
// 72.249 us; speedup vs baseline: 1.3936x; 1.0067x over previous
//
#include <hip/hip_runtime.h>
#include <hip/hip_bf16.h>
#include <stdint.h>

// ComplexDFT256: out(65536x512) = X(65536x512) @ W^T, W = [[cos,-sin],[sin,cos]].
// Transposed MFMA (D[j][b]); whole X block-tile staged in LDS in 2 phases,
// compute phases run barrier-free (2 barriers/block total).

typedef __attribute__((ext_vector_type(8))) short bf16x8;
typedef __attribute__((ext_vector_type(4))) float f32x4;

#define KDIM 512
#define NDIM 512
#define BM 64

__device__ __forceinline__ ushort f2bf(float f) {
  union { float f; uint32_t u; } v; v.f = f;
  uint32_t r = (v.u + 0x7fffu + ((v.u >> 16) & 1u)) >> 16;  // RNE
  return (ushort)r;
}

// Fragment-ordered W: Wf[8*g .. 8*g+7], g = k5*2048 + nt*64 + lane, holds
// W[j = nt*16 + (lane&15)][k = k5*32 + (lane>>4)*8 + e]  (e = 0..7)
__global__ __launch_bounds__(512) void build_w_kernel(const float* __restrict__ cosk,
                                                      const float* __restrict__ sink,
                                                      ushort* __restrict__ Wf) {
  int g = blockIdx.x * 512 + threadIdx.x;   // 0..32767
  int lane = g & 63;
  int nt = (g >> 6) & 31;
  int j = nt * 16 + (lane & 15);
  int kbase = (g >> 11) * 32 + (lane >> 4) * 8;
  bf16x8 w8;
#pragma unroll
  for (int e = 0; e < 8; ++e) {
    int k = kbase + e;
    float v;
    if (j < 256) {
      v = (k < 256) ? cosk[(j << 8) + k] : -sink[(j << 8) + (k - 256)];
    } else {
      int jj = j - 256;
      v = (k < 256) ? sink[(jj << 8) + k] : cosk[(jj << 8) + (k - 256)];
    }
    w8[e] = (short)f2bf(v);
  }
  *reinterpret_cast<bf16x8*>(Wf + (size_t)g * 8) = w8;
}

__device__ __forceinline__ bf16x8 cvt8(f32x4 a, f32x4 b) {
  bf16x8 w8;
  w8[0] = (short)f2bf(a[0]); w8[1] = (short)f2bf(a[1]);
  w8[2] = (short)f2bf(a[2]); w8[3] = (short)f2bf(a[3]);
  w8[4] = (short)f2bf(b[0]); w8[5] = (short)f2bf(b[1]);
  w8[6] = (short)f2bf(b[2]); w8[7] = (short)f2bf(b[3]);
  return w8;
}

// Block = 64 batch rows x full 512 output cols, 8 waves (each 64 j x 64 b).
// LDS = 8 K-subtiles (64x64 bf16 each, XOR-swizzled), 64 KB -> 2 blocks/CU.
__global__ __launch_bounds__(512, 4) void dft_gemm_kernel(const float* __restrict__ A,
                                                          const ushort* __restrict__ Wf,
                                                          float* __restrict__ out) {
  __shared__ ushort As[8][64 * 64];   // 64 KB

  const int tid  = threadIdx.x;
  const int lane = tid & 63;
  const int wid  = tid >> 6;            // 0..7
  const int m0   = blockIdx.x * BM;
  const int c0   = wid * 64;            // j base for this wave

  // staging: each thread owns 8 floats of one row per K-subtile
  const int srow = tid >> 3;
  const int skq  = (tid & 7) * 8;
  const float* ap = A + (size_t)(m0 + srow) * KDIM + skq;
  const int swb = (srow << 6) + (skq ^ ((srow & 7) << 3));

  const int lrow = lane & 15;
  const int lk8  = (lane >> 4) * 8;

  // W frag base: (k5*32 + nt)*512 + lane*8; nt = c0/16 + mi, k5 = t*2 + kk
  const ushort* wp = Wf + (size_t)(c0 >> 4) * 512 + lane * 8;

  f32x4 acc[4][4] = {};   // [mi = j-tile][ni = b-tile]

  // ---- phase 0: stage K-subtiles 0..3 (8 loads in flight, then cvt+write) ----
  {
    f32x4 s[8];
#pragma unroll
    for (int t = 0; t < 4; ++t) {
      s[2 * t]     = *reinterpret_cast<const f32x4*>(ap + t * 64);
      s[2 * t + 1] = *reinterpret_cast<const f32x4*>(ap + t * 64 + 4);
    }
#pragma unroll
    for (int t = 0; t < 4; ++t)
      *reinterpret_cast<bf16x8*>(&As[t][swb]) = cvt8(s[2 * t], s[2 * t + 1]);
  }
  asm volatile("s_waitcnt lgkmcnt(0)" ::: "memory");
  __builtin_amdgcn_s_barrier();

  // ---- compute steps 0..3: no barriers, waves free-run ----
#pragma unroll
  for (int t = 0; t < 4; ++t) {
    bf16x8 wfr[2][4];
#pragma unroll
    for (int kk = 0; kk < 2; ++kk)
#pragma unroll
      for (int mi = 0; mi < 4; ++mi)
        wfr[kk][mi] = *reinterpret_cast<const bf16x8*>(
            wp + (size_t)((t * 2 + kk) * 32 + mi) * 512);
#pragma unroll
    for (int kk = 0; kk < 2; ++kk) {
      bf16x8 xfr[4];
#pragma unroll
      for (int ni = 0; ni < 4; ++ni) {
        int row = ni * 16 + lrow;
        int idx = (row << 6) + ((kk * 32 + lk8) ^ ((lrow & 7) << 3));
        xfr[ni] = *reinterpret_cast<const bf16x8*>(&As[t][idx]);
      }
#pragma unroll
      for (int mi = 0; mi < 4; ++mi)
#pragma unroll
        for (int ni = 0; ni < 4; ++ni)
          acc[mi][ni] = __builtin_amdgcn_mfma_f32_16x16x32_bf16(
              wfr[kk][mi], xfr[ni], acc[mi][ni], 0, 0, 0);
    }
  }

  // ---- phase 1: stage K-subtiles 4..7 ----
  {
    f32x4 s[8];
#pragma unroll
    for (int t = 0; t < 4; ++t) {
      s[2 * t]     = *reinterpret_cast<const f32x4*>(ap + (4 + t) * 64);
      s[2 * t + 1] = *reinterpret_cast<const f32x4*>(ap + (4 + t) * 64 + 4);
    }
#pragma unroll
    for (int t = 0; t < 4; ++t)
      *reinterpret_cast<bf16x8*>(&As[4 + t][swb]) = cvt8(s[2 * t], s[2 * t + 1]);
  }
  asm volatile("s_waitcnt lgkmcnt(0)" ::: "memory");
  __builtin_amdgcn_s_barrier();

  // ---- compute steps 4..7 ----
#pragma unroll
  for (int t = 4; t < 8; ++t) {
    bf16x8 wfr[2][4];
#pragma unroll
    for (int kk = 0; kk < 2; ++kk)
#pragma unroll
      for (int mi = 0; mi < 4; ++mi)
        wfr[kk][mi] = *reinterpret_cast<const bf16x8*>(
            wp + (size_t)((t * 2 + kk) * 32 + mi) * 512);
#pragma unroll
    for (int kk = 0; kk < 2; ++kk) {
      bf16x8 xfr[4];
#pragma unroll
      for (int ni = 0; ni < 4; ++ni) {
        int row = ni * 16 + lrow;
        int idx = (row << 6) + ((kk * 32 + lk8) ^ ((lrow & 7) << 3));
        xfr[ni] = *reinterpret_cast<const bf16x8*>(&As[t][idx]);
      }
#pragma unroll
      for (int mi = 0; mi < 4; ++mi)
#pragma unroll
        for (int ni = 0; ni < 4; ++ni)
          acc[mi][ni] = __builtin_amdgcn_mfma_f32_16x16x32_bf16(
              wfr[kk][mi], xfr[ni], acc[mi][ni], 0, 0, 0);
    }
  }

  // ---- epilogue: lane holds 4 contiguous j's -> f32x4 stores ----
  const int jbase = c0 + (lane >> 4) * 4;
#pragma unroll
  for (int ni = 0; ni < 4; ++ni) {
    size_t rowb = (size_t)(m0 + ni * 16 + lrow) * NDIM;
#pragma unroll
    for (int mi = 0; mi < 4; ++mi)
      *reinterpret_cast<f32x4*>(out + rowb + jbase + mi * 16) = acc[mi][ni];
  }
}

extern "C" void kernel_launch(void* const* d_in, const int* in_sizes, int n_in,
                              void* d_out, int out_size, void* d_ws, size_t ws_size,
                              hipStream_t stream) {
  const float* x    = (const float*)d_in[0];   // (65536, 2, 256) fp32
  const float* cosk = (const float*)d_in[1];   // (256, 256) fp32
  const float* sink = (const float*)d_in[2];   // (256, 256) fp32
  float* out = (float*)d_out;                  // (65536, 512, 1) fp32
  ushort* Wf = (ushort*)d_ws;                  // 512 KB fragment-ordered W

  build_w_kernel<<<64, 512, 0, stream>>>(cosk, sink, Wf);
  dft_gemm_kernel<<<65536 / BM, 512, 0, stream>>>(x, Wf, out);
}

// Round 7
// 70.238 us; speedup vs baseline: 1.4335x; 1.0286x over previous
//
#include <hip/hip_runtime.h>
#include <hip/hip_bf16.h>
#include <stdint.h>

// ComplexDFT256: out(65536x512) = X(65536x512) @ W^T, W = [[cos,-sin],[sin,cos]].
// Transposed MFMA (D[j][b]); BM=128 (acc[4][8]) doubles MFMAs per W byte;
// W frags half-step register ping-pong; X per-step double-buffered LDS.

typedef __attribute__((ext_vector_type(8))) short bf16x8;
typedef __attribute__((ext_vector_type(4))) float f32x4;

#define KDIM 512
#define NDIM 512
#define BM 128

__device__ __forceinline__ ushort f2bf(float f) {
  union { float f; uint32_t u; } v; v.f = f;
  uint32_t r = (v.u + 0x7fffu + ((v.u >> 16) & 1u)) >> 16;  // RNE
  return (ushort)r;
}

// Fragment-ordered W: Wf[8*g .. 8*g+7], g = k5*2048 + nt*64 + lane, holds
// W[j = nt*16 + (lane&15)][k = k5*32 + (lane>>4)*8 + e]  (e = 0..7)
__global__ __launch_bounds__(512) void build_w_kernel(const float* __restrict__ cosk,
                                                      const float* __restrict__ sink,
                                                      ushort* __restrict__ Wf) {
  int g = blockIdx.x * 512 + threadIdx.x;   // 0..32767
  int lane = g & 63;
  int nt = (g >> 6) & 31;
  int j = nt * 16 + (lane & 15);
  int kbase = (g >> 11) * 32 + (lane >> 4) * 8;
  bf16x8 w8;
#pragma unroll
  for (int e = 0; e < 8; ++e) {
    int k = kbase + e;
    float v;
    if (j < 256) {
      v = (k < 256) ? cosk[(j << 8) + k] : -sink[(j << 8) + (k - 256)];
    } else {
      int jj = j - 256;
      v = (k < 256) ? sink[(jj << 8) + k] : cosk[(jj << 8) + (k - 256)];
    }
    w8[e] = (short)f2bf(v);
  }
  *reinterpret_cast<bf16x8*>(Wf + (size_t)g * 8) = w8;
}

__device__ __forceinline__ bf16x8 cvt8(f32x4 a, f32x4 b) {
  bf16x8 w8;
  w8[0] = (short)f2bf(a[0]); w8[1] = (short)f2bf(a[1]);
  w8[2] = (short)f2bf(a[2]); w8[3] = (short)f2bf(a[3]);
  w8[4] = (short)f2bf(b[0]); w8[5] = (short)f2bf(b[1]);
  w8[6] = (short)f2bf(b[2]); w8[7] = (short)f2bf(b[3]);
  return w8;
}

// Block = 128 batch rows x full 512 j, 8 waves (each 64 j x 128 batch).
// LDS: 2 x (128 rows x 64 k) bf16 subtiles, XOR-swizzled, 32 KB.
__global__ __launch_bounds__(512, 2) void dft_gemm_kernel(const float* __restrict__ A,
                                                          const ushort* __restrict__ Wf,
                                                          float* __restrict__ out) {
  __shared__ ushort As[2][BM * 64];   // 2 x 16 KB

  const int tid  = threadIdx.x;
  const int lane = tid & 63;
  const int wid  = tid >> 6;            // 0..7
  const int m0   = blockIdx.x * BM;
  const int c0   = wid * 64;            // j base for this wave

  // staging: thread owns 16 consecutive floats of one row per K-subtile
  const int srow  = tid >> 2;           // 0..127
  const int skq   = (tid & 3) * 16;     // float offset within 64-wide subtile
  const float* ap = A + (size_t)(m0 + srow) * KDIM + skq;
  const int slot0 = (tid & 3) * 2;      // 8-elem slot index (0,2,4,6)
  const int eA = srow * 64 + (((slot0)     ^ (srow & 7)) << 3);
  const int eB = srow * 64 + (((slot0 + 1) ^ (srow & 7)) << 3);

  const int lrow = lane & 15;
  const int lk8  = (lane >> 4) * 8;

  // W frag base: ((t*2+kk)*32 + nt)*512 + lane*8; nt = c0/16 + mi
  const ushort* wp = Wf + (size_t)(c0 >> 4) * 512 + lane * 8;

  f32x4 acc[4][8] = {};   // [mi = j-tile][ni = batch-tile]

  // ---- prologue: stage subtile 0, preload W(t=0,kk=0) ----
  {
    f32x4 s0 = *reinterpret_cast<const f32x4*>(ap);
    f32x4 s1 = *reinterpret_cast<const f32x4*>(ap + 4);
    f32x4 s2 = *reinterpret_cast<const f32x4*>(ap + 8);
    f32x4 s3 = *reinterpret_cast<const f32x4*>(ap + 12);
    *reinterpret_cast<bf16x8*>(&As[0][eA]) = cvt8(s0, s1);
    *reinterpret_cast<bf16x8*>(&As[0][eB]) = cvt8(s2, s3);
  }
  bf16x8 wcur[4];
#pragma unroll
  for (int mi = 0; mi < 4; ++mi)
    wcur[mi] = *reinterpret_cast<const bf16x8*>(wp + (size_t)mi * 512);
  asm volatile("s_waitcnt lgkmcnt(0)" ::: "memory");
  __builtin_amdgcn_s_barrier();

#pragma unroll
  for (int t = 0; t < 8; ++t) {
    // issue X loads for subtile t+1 (consumed by ds_write after kk=1)
    f32x4 x0, x1, x2, x3;
    if (t < 7) {
      const float* apn = ap + (t + 1) * 64;
      x0 = *reinterpret_cast<const f32x4*>(apn);
      x1 = *reinterpret_cast<const f32x4*>(apn + 4);
      x2 = *reinterpret_cast<const f32x4*>(apn + 8);
      x3 = *reinterpret_cast<const f32x4*>(apn + 12);
    }

    // prefetch W for kk=1 while computing kk=0
    bf16x8 wnxt[4];
#pragma unroll
    for (int mi = 0; mi < 4; ++mi)
      wnxt[mi] = *reinterpret_cast<const bf16x8*>(
          wp + (size_t)((t * 2 + 1) * 32 + mi) * 512);

    // ---- kk = 0 ----
    {
      bf16x8 xfr[8];
#pragma unroll
      for (int ni = 0; ni < 8; ++ni) {
        int row = ni * 16 + lrow;
        int idx = (row << 6) + (lk8 ^ ((lrow & 7) << 3));
        xfr[ni] = *reinterpret_cast<const bf16x8*>(&As[t & 1][idx]);
      }
#pragma unroll
      for (int mi = 0; mi < 4; ++mi)
#pragma unroll
        for (int ni = 0; ni < 8; ++ni)
          acc[mi][ni] = __builtin_amdgcn_mfma_f32_16x16x32_bf16(
              wcur[mi], xfr[ni], acc[mi][ni], 0, 0, 0);
    }

    // prefetch W for (t+1, kk=0) while computing kk=1
    if (t < 7) {
#pragma unroll
      for (int mi = 0; mi < 4; ++mi)
        wcur[mi] = *reinterpret_cast<const bf16x8*>(
            wp + (size_t)((t * 2 + 2) * 32 + mi) * 512);
    }

    // ---- kk = 1 ----
    {
      bf16x8 xfr[8];
#pragma unroll
      for (int ni = 0; ni < 8; ++ni) {
        int row = ni * 16 + lrow;
        int idx = (row << 6) + ((32 + lk8) ^ ((lrow & 7) << 3));
        xfr[ni] = *reinterpret_cast<const bf16x8*>(&As[t & 1][idx]);
      }
#pragma unroll
      for (int mi = 0; mi < 4; ++mi)
#pragma unroll
        for (int ni = 0; ni < 8; ++ni)
          acc[mi][ni] = __builtin_amdgcn_mfma_f32_16x16x32_bf16(
              wnxt[mi], xfr[ni], acc[mi][ni], 0, 0, 0);
    }

    // stage subtile t+1 into other buffer; one lgkm-only barrier per step
    if (t < 7) {
      *reinterpret_cast<bf16x8*>(&As[(t + 1) & 1][eA]) = cvt8(x0, x1);
      *reinterpret_cast<bf16x8*>(&As[(t + 1) & 1][eB]) = cvt8(x2, x3);
      asm volatile("s_waitcnt lgkmcnt(0)" ::: "memory");
      __builtin_amdgcn_s_barrier();
    }
  }

  // ---- epilogue: lane holds 4 contiguous j's -> f32x4 stores ----
  const int jbase = c0 + (lane >> 4) * 4;
#pragma unroll
  for (int ni = 0; ni < 8; ++ni) {
    size_t rowb = (size_t)(m0 + ni * 16 + lrow) * NDIM;
#pragma unroll
    for (int mi = 0; mi < 4; ++mi)
      *reinterpret_cast<f32x4*>(out + rowb + jbase + mi * 16) = acc[mi][ni];
  }
}

extern "C" void kernel_launch(void* const* d_in, const int* in_sizes, int n_in,
                              void* d_out, int out_size, void* d_ws, size_t ws_size,
                              hipStream_t stream) {
  const float* x    = (const float*)d_in[0];   // (65536, 2, 256) fp32
  const float* cosk = (const float*)d_in[1];   // (256, 256) fp32
  const float* sink = (const float*)d_in[2];   // (256, 256) fp32
  float* out = (float*)d_out;                  // (65536, 512, 1) fp32
  ushort* Wf = (ushort*)d_ws;                  // 512 KB fragment-ordered W

  build_w_kernel<<<64, 512, 0, stream>>>(cosk, sink, Wf);
  dft_gemm_kernel<<<65536 / BM, 512, 0, stream>>>(x, Wf, out);
}